// Round 18
// baseline (442.543 us; speedup 1.0000x reference)
//
#include <hip/hip_runtime.h>
#include <hip/hip_bf16.h>

typedef unsigned short u16;
typedef unsigned int u32;
typedef unsigned long long u64;
typedef __attribute__((ext_vector_type(8))) short short8;
typedef __attribute__((ext_vector_type(4))) float floatx4;

#define MFMA16(a,b,c) __builtin_amdgcn_mfma_f32_16x16x32_bf16((a),(b),(c),0,0,0)

__device__ __forceinline__ u16 f2bf(float f){
  u32 x = __float_as_uint(f);
  x += 0x7FFFu + ((x >> 16) & 1u);
  return (u16)(x >> 16);
}
__device__ __forceinline__ float frcp(float x){ return __builtin_amdgcn_rcpf(x); }
__device__ __forceinline__ float fexp2(float x){ return __builtin_amdgcn_exp2f(x); }
// 0.125 * log2(e): scale folded into the exp2 argument
#define KEXP 0.18033688011112042f
#define Z4 ((floatx4){0.f,0.f,0.f,0.f})

// async global->LDS 16B per lane: LDS dest = wave-uniform base + lane*16,
// global src is per-lane (pre-swizzled source pattern).
__device__ __forceinline__ void gl_lds16(const u16* src, u16* dst){
  __builtin_amdgcn_global_load_lds(
      (const __attribute__((address_space(1))) unsigned int*)(u64)(src),
      (__attribute__((address_space(3))) unsigned int*)(u32)(u64)(dst),
      16, 0, 0);
}

// ---------------- weight transpose+convert (all 6): wt[z][j][d] = bf16(w[z][d][j]) ----
__global__ __launch_bounds__(256) void k_wt6(
    const float* __restrict__ w0, const float* __restrict__ w1, const float* __restrict__ w2,
    const float* __restrict__ w3, const float* __restrict__ w4, const float* __restrict__ w5,
    u16* __restrict__ wts)
{
  int z = blockIdx.y;
  const float* w;
  switch (z){ case 0: w = w0; break; case 1: w = w1; break; case 2: w = w2; break;
              case 3: w = w3; break; case 4: w = w4; break; default: w = w5; break; }
  int idx = blockIdx.x * 256 + threadIdx.x;
  int j = idx >> 9, d = idx & 511;
  wts[(size_t)z * 262144 + idx] = f2bf(w[d * 512 + j]);
}

// ---------------- fused projection GEMM, 128x128 tile, dual-output -------------------
// z=0: xq -> {Q(wq,bq), Q1(wq1,bq1)}; z=1: xk -> {K, K1}; z=2: xv -> Vt (transposed).
// A (f32 input) staged ONCE per k-step serves both outputs -> x reads halve (168->100MB).
// B via gl_lds16 (linear dest + XOR-swizzled src); bf frags loaded per-set sequentially.
__global__ __launch_bounds__(256) void k_proj3(
    const float* __restrict__ xq, const float* __restrict__ xk, const float* __restrict__ xv,
    const u16* __restrict__ wts,
    const float* __restrict__ bq, const float* __restrict__ bk, const float* __restrict__ bv,
    const float* __restrict__ bq1, const float* __restrict__ bk1,
    u16* __restrict__ Qh, u16* __restrict__ Kh, u16* __restrict__ Vt,
    u16* __restrict__ Q1h, u16* __restrict__ K1h)
{
  __shared__ __align__(16) u16 As[128][72];
  __shared__ __align__(16) u16 Bs0[128 * 64];
  __shared__ __align__(16) u16 Bs1[128 * 64];
  const int z = blockIdx.z;
  const float* x; const float* bias0; const float* bias1 = nullptr;
  const u16* wtA; const u16* wtB = nullptr;
  u16* out0; u16* out1 = nullptr; int vtm = 0;
  if (z == 0){ x = xq; wtA = wts;                wtB = wts + 3 * 262144;
               bias0 = bq; bias1 = bq1; out0 = Qh; out1 = Q1h; }
  else if (z == 1){ x = xk; wtA = wts + 262144;  wtB = wts + 4 * 262144;
               bias0 = bk; bias1 = bk1; out0 = Kh; out1 = K1h; }
  else { x = xv; wtA = wts + 2 * 262144; bias0 = bv; out0 = Vt; vtm = 1; }

  const int tid = threadIdx.x, lane = tid & 63, wid = tid >> 6;
  const int wm = wid >> 1, wn = wid & 1;
  const int m0 = blockIdx.x * 128, n0 = blockIdx.y * 128;
  const int arow = lane & 15, kg = lane >> 4;
  const int ar = tid >> 1, ah = (tid & 1) * 32;
  const int br = tid >> 3, bc = tid & 7;

  floatx4 acc0[4][4], acc1[4][4];
  #pragma unroll
  for (int i = 0; i < 4; ++i)
    #pragma unroll
    for (int j = 0; j < 4; ++j){ acc0[i][j] = Z4; acc1[i][j] = Z4; }

  for (int k0 = 0; k0 < 512; k0 += 64){
    #pragma unroll
    for (int q = 0; q < 4; ++q)
      gl_lds16(wtA + (size_t)(n0 + q * 32 + br) * 512 + k0 + ((bc ^ (br & 7)) * 8),
               Bs0 + wid * 512 + q * 2048);
    if (z < 2){
      #pragma unroll
      for (int q = 0; q < 4; ++q)
        gl_lds16(wtB + (size_t)(n0 + q * 32 + br) * 512 + k0 + ((bc ^ (br & 7)) * 8),
                 Bs1 + wid * 512 + q * 2048);
    }
    const float4* xp = (const float4*)(x + (size_t)(m0 + ar) * 512 + k0 + ah);
    #pragma unroll
    for (int j = 0; j < 4; ++j){
      float4 f0 = xp[2 * j], f1 = xp[2 * j + 1];
      short8 v;
      v[0] = (short)f2bf(f0.x); v[1] = (short)f2bf(f0.y);
      v[2] = (short)f2bf(f0.z); v[3] = (short)f2bf(f0.w);
      v[4] = (short)f2bf(f1.x); v[5] = (short)f2bf(f1.y);
      v[6] = (short)f2bf(f1.z); v[7] = (short)f2bf(f1.w);
      *(short8*)&As[ar][ah + j * 8] = v;
    }
    __syncthreads();
    #pragma unroll
    for (int kk = 0; kk < 2; ++kk){
      short8 af[4];
      #pragma unroll
      for (int mm = 0; mm < 4; ++mm)
        af[mm] = *(const short8*)&As[wm * 64 + mm * 16 + arow][kk * 32 + kg * 8];
      {
        short8 bf[4];
        #pragma unroll
        for (int nn = 0; nn < 4; ++nn){
          int rr = wn * 64 + nn * 16 + arow;
          bf[nn] = *(const short8*)&Bs0[rr * 64 + ((kk * 32 + kg * 8) ^ ((rr & 7) * 8))];
        }
        #pragma unroll
        for (int mm = 0; mm < 4; ++mm)
          #pragma unroll
          for (int nn = 0; nn < 4; ++nn)
            acc0[mm][nn] = MFMA16(af[mm], bf[nn], acc0[mm][nn]);
      }
      if (z < 2){
        short8 bf[4];
        #pragma unroll
        for (int nn = 0; nn < 4; ++nn){
          int rr = wn * 64 + nn * 16 + arow;
          bf[nn] = *(const short8*)&Bs1[rr * 64 + ((kk * 32 + kg * 8) ^ ((rr & 7) * 8))];
        }
        #pragma unroll
        for (int mm = 0; mm < 4; ++mm)
          #pragma unroll
          for (int nn = 0; nn < 4; ++nn)
            acc1[mm][nn] = MFMA16(af[mm], bf[nn], acc1[mm][nn]);
      }
    }
    __syncthreads();
  }
  #pragma unroll
  for (int mm = 0; mm < 4; ++mm)
    #pragma unroll
    for (int nn = 0; nn < 4; ++nn){
      int j = n0 + wn * 64 + nn * 16 + arow;
      int h = j >> 6, dh = j & 63;
      float b0v = bias0[j];
      #pragma unroll
      for (int i = 0; i < 4; ++i){
        int sg = m0 + wm * 64 + mm * 16 + kg * 4 + i;
        int bb = sg >> 10, s = sg & 1023;
        float val = acc0[mm][nn][i] + b0v;
        size_t o = vtm ? (((size_t)((bb << 3) + h) * 64 + dh) * 1024 + s)
                       : (((size_t)((bb << 3) + h) * 1024 + s) * 64 + dh);
        out0[o] = f2bf(val);
      }
      if (z < 2){
        float b1v = bias1[j];
        #pragma unroll
        for (int i = 0; i < 4; ++i){
          int sg = m0 + wm * 64 + mm * 16 + kg * 4 + i;
          int bb = sg >> 10, s = sg & 1023;
          float val = acc1[mm][nn][i] + b1v;
          out1[(((size_t)((bb << 3) + h) * 1024 + s) * 64 + dh)] = f2bf(val);
        }
      }
    }
}

// ================= SPLIT PATH =================
// ---------------- kernel A (R17-proven): k-outer / q-inner dual-QK -> U, rsum --------
__global__ void __launch_bounds__(1024)
k_qk(const u16* __restrict__ Qh, const u16* __restrict__ Kh,
     const u16* __restrict__ Q1h, const u16* __restrict__ K1h,
     const int* __restrict__ mask, u16* __restrict__ U, float* __restrict__ rsum)
{
  __shared__ __align__(16) u16 stg[2 * 8192];

  const int tid = threadIdx.x, lane = tid & 63, wid = tid >> 6;
  const int arow = lane & 15, kg = lane >> 4;
  const int b = blockIdx.x, h = blockIdx.y, qs = blockIdx.z;
  const size_t hb = (size_t)(b * 8 + h);

  const int qrow = qs * 256 + wid * 16 + arow;
  const u16* qp  = Qh  + (hb * 1024 + qrow) * 64 + kg * 8;
  const u16* q1p = Q1h + (hb * 1024 + qrow) * 64 + kg * 8;
  short8 aq0 = *(const short8*)qp,  aq1 = *(const short8*)(qp + 32);
  short8 ap0 = *(const short8*)q1p, ap1 = *(const short8*)(q1p + 32);

  u64 mb = 0;
  #pragma unroll
  for (int t = 0; t < 16; ++t)
    #pragma unroll
    for (int cs = 0; cs < 4; ++cs)
      mb |= (mask[b * 1024 + t * 64 + cs * 16 + arow] != 0 ? 1ull : 0ull) << (t * 4 + cs);

  const int ls_half = tid >> 9;
  const int ls_r = (tid & 511) >> 3;
  const int ls_c = (tid & 7) ^ (ls_r & 7);
  u16* const sbase = stg + wid * 512;
  const u16* lsrc = (ls_half ? Kh : K1h) + hb * 65536 + (size_t)ls_r * 64 + ls_c * 8;

  u16* const ubase = U + hb * 1048576;
  const int urow0 = qs * 256 + wid * 16 + kg * 4;

  gl_lds16(lsrc, sbase);
  __syncthreads();

  float sacc[4] = {0.f, 0.f, 0.f, 0.f};
  for (int t = 0; t < 16; ++t){
    if (t < 15)
      gl_lds16(lsrc + (size_t)(t + 1) * 4096, sbase + (((t + 1) & 1) << 13));
    const u16* kb = stg + ((t & 1) << 13);
    #pragma unroll
    for (int cs = 0; cs < 4; ++cs){
      const int krow = cs * 16 + arow;
      const int swl = (krow & 7) * 8;
      short8 b1a = *(const short8*)&kb[krow * 64 + ((     kg * 8) ^ swl)];
      short8 b1b = *(const short8*)&kb[krow * 64 + ((32 + kg * 8) ^ swl)];
      short8 bea = *(const short8*)&kb[4096 + krow * 64 + ((     kg * 8) ^ swl)];
      short8 beb = *(const short8*)&kb[4096 + krow * 64 + ((32 + kg * 8) ^ swl)];
      floatx4 cg4 = Z4, ce4 = Z4;
      cg4 = MFMA16(ap0, b1a, cg4); cg4 = MFMA16(ap1, b1b, cg4);
      ce4 = MFMA16(aq0, bea, ce4); ce4 = MFMA16(aq1, beb, ce4);
      const float msk = ((mb >> (t * 4 + cs)) & 1ull) ? 1.0f : 0.0f;
      #pragma unroll
      for (int i = 0; i < 4; ++i){
        float p = fexp2(ce4[i] * KEXP) * msk;
        float g = frcp(1.0f + fexp2(-cg4[i] * KEXP));
        sacc[i] += p;
        ubase[(size_t)(urow0 + i) * 1024 + t * 64 + cs * 16 + arow] = f2bf(p * g);
      }
    }
    __syncthreads();
  }

  #pragma unroll
  for (int i = 0; i < 4; ++i){
    #pragma unroll
    for (int off = 1; off <= 8; off <<= 1)
      sacc[i] += __shfl_xor(sacc[i], off, 64);
  }
  if (arow == 0){
    #pragma unroll
    for (int i = 0; i < 4; ++i)
      rsum[hb * 1024 + urow0 + i] = sacc[i];
  }
}

// ---------------- kernel B (R16-proven, 173 us): r_att + PV from STAGED U ------------
// grid (16 b, 32 qt); 512 thr (8 waves); 48 KB LDS dbuf -> 2 blocks/CU.
__global__ void __launch_bounds__(512)
__attribute__((amdgpu_waves_per_eu(4, 4)))
k_pvr(const u16* __restrict__ U, const float* __restrict__ rsum,
      const u16* __restrict__ Vt, u16* __restrict__ xa, float* __restrict__ ratt)
{
  extern __shared__ __align__(16) u16 stg2[];   // 2 bufs x 12288 u16: U[0,4096) V[4096,12288)

  const int tid = threadIdx.x, lane = tid & 63, wid = tid >> 6;
  const int arow = lane & 15, kg = lane >> 4;
  const int b = blockIdx.x, qt = blockIdx.y;
  const int s2 = wid & 1, cg = wid >> 1;
  const int cres = cg * 16 + arow;          // dh residue
  const int wrow = wid * 4;                 // racc rows
  const int a_r = s2 * 16 + arow;           // PV A row in U slice

  const int ur = tid >> 4, uc = (tid & 15) ^ (ur & 7);
  const int vr0 = tid >> 4, vc0 = (tid & 15) ^ (vr0 & 7);
  const int vr1 = vr0 + 32, vc1 = (tid & 15) ^ (vr1 & 7);

  float racc[4][16];
  #pragma unroll
  for (int r = 0; r < 4; ++r)
    #pragma unroll
    for (int j = 0; j < 16; ++j) racc[r][j] = 0.f;

  for (int h = 0; h < 8; ++h){
    const size_t hb = (size_t)(b * 8 + h);
    const u16* ub = U  + hb * 1048576 + (size_t)(qt * 32) * 1024;
    const u16* vb = Vt + hb * 65536;

    float rlh[4], rlx[4];
    #pragma unroll
    for (int r = 0; r < 4; ++r)
      rlh[r] = frcp(rsum[hb * 1024 + qt * 32 + wrow + r]) * 0.125f;
    #pragma unroll
    for (int i = 0; i < 4; ++i)
      rlx[i] = frcp(rsum[hb * 1024 + qt * 32 + s2 * 16 + kg * 4 + i]);

    gl_lds16(ub + (size_t)ur * 1024 + uc * 8,  stg2 + tid * 8);
    gl_lds16(vb + (size_t)vr0 * 1024 + vc0 * 8, stg2 + 4096 + tid * 8);
    gl_lds16(vb + (size_t)vr1 * 1024 + vc1 * 8, stg2 + 8192 + tid * 8);
    __syncthreads();

    floatx4 cpv = Z4;
    for (int t = 0; t < 8; ++t){
      if (t < 7){
        const int nb = ((t + 1) & 1) * 12288;
        gl_lds16(ub + (size_t)ur * 1024 + (t + 1) * 128 + uc * 8,  stg2 + nb + tid * 8);
        gl_lds16(vb + (size_t)vr0 * 1024 + (t + 1) * 128 + vc0 * 8, stg2 + nb + 4096 + tid * 8);
        gl_lds16(vb + (size_t)vr1 * 1024 + (t + 1) * 128 + vc1 * 8, stg2 + nb + 8192 + tid * 8);
      }
      const u16* Ut  = stg2 + (t & 1) * 12288;
      const u16* Vts = Ut + 4096;
      #pragma unroll
      for (int r = 0; r < 4; ++r){
        const int row = wrow + r;
        u32 w = *(const u32*)&Ut[row * 128 + ((lane * 2) ^ ((row & 7) * 8))];
        racc[r][2 * t]     += __uint_as_float(w << 16) * rlh[r];
        racc[r][2 * t + 1] += __uint_as_float(w & 0xFFFF0000u) * rlh[r];
      }
      #pragma unroll
      for (int ks = 0; ks < 4; ++ks){
        short8 a  = *(const short8*)&Ut[a_r * 128 + ((ks * 32 + kg * 8) ^ ((a_r & 7) * 8))];
        short8 bv = *(const short8*)&Vts[cres * 128 + ((ks * 32 + kg * 8) ^ ((cres & 7) * 8))];
        cpv = MFMA16(a, bv, cpv);
      }
      __syncthreads();
    }
    #pragma unroll
    for (int i = 0; i < 4; ++i){
      const int g = qt * 32 + s2 * 16 + kg * 4 + i;
      xa[((size_t)(b * 1024 + g)) * 512 + h * 64 + cres] = f2bf(cpv[i] * rlx[i]);
    }
  }

  #pragma unroll
  for (int r = 0; r < 4; ++r){
    const size_t rb = ((size_t)(b * 1024 + qt * 32 + wrow + r)) * 1024;
    #pragma unroll
    for (int j = 0; j < 8; ++j){
      float2 v = {racc[r][2 * j], racc[r][2 * j + 1]};
      *(float2*)&ratt[rb + j * 128 + lane * 2] = v;
    }
  }
}

// ---------------- final FC, 128x128 tile (R14-proven) ----------------
__global__ __launch_bounds__(256) void k_fc(
    const u16* __restrict__ xa, const u16* __restrict__ wt,
    const float* __restrict__ bias, float* __restrict__ out)
{
  __shared__ __align__(16) u16 Asf[128 * 64];
  __shared__ __align__(16) u16 Bsf[128 * 64];
  const int tid = threadIdx.x, lane = tid & 63, wid = tid >> 6;
  const int wm = wid >> 1, wn = wid & 1;
  const int m0 = blockIdx.x * 128, n0 = blockIdx.y * 128;
  const int arow = lane & 15, kg = lane >> 4;
  const int br = tid >> 3, bc = tid & 7;
  u16* const adst = Asf + wid * 512;
  u16* const bdst = Bsf + wid * 512;

  floatx4 acc[4][4];
  #pragma unroll
  for (int i = 0; i < 4; ++i)
    #pragma unroll
    for (int j = 0; j < 4; ++j) acc[i][j] = Z4;

  for (int k0 = 0; k0 < 512; k0 += 64){
    #pragma unroll
    for (int q = 0; q < 4; ++q){
      gl_lds16(xa + (size_t)(m0 + q * 32 + br) * 512 + k0 + ((bc ^ (br & 7)) * 8),
               adst + q * 2048);
      gl_lds16(wt + (size_t)(n0 + q * 32 + br) * 512 + k0 + ((bc ^ (br & 7)) * 8),
               bdst + q * 2048);
    }
    __syncthreads();
    #pragma unroll
    for (int kk = 0; kk < 2; ++kk){
      short8 af[4], bf[4];
      #pragma unroll
      for (int mm = 0; mm < 4; ++mm){
        int rr = wm * 64 + mm * 16 + arow;
        af[mm] = *(const short8*)&Asf[rr * 64 + ((kk * 32 + kg * 8) ^ ((rr & 7) * 8))];
      }
      #pragma unroll
      for (int nn = 0; nn < 4; ++nn){
        int rr = wn * 64 + nn * 16 + arow;
        bf[nn] = *(const short8*)&Bsf[rr * 64 + ((kk * 32 + kg * 8) ^ ((rr & 7) * 8))];
      }
      #pragma unroll
      for (int mm = 0; mm < 4; ++mm)
        #pragma unroll
        for (int nn = 0; nn < 4; ++nn)
          acc[mm][nn] = MFMA16(af[mm], bf[nn], acc[mm][nn]);
    }
    __syncthreads();
  }
  #pragma unroll
  for (int mm = 0; mm < 4; ++mm)
    #pragma unroll
    for (int nn = 0; nn < 4; ++nn){
      int j = n0 + wn * 64 + nn * 16 + arow;
      float bval = bias[j];
      #pragma unroll
      for (int i = 0; i < 4; ++i){
        int sg = m0 + wm * 64 + mm * 16 + kg * 4 + i;
        out[(size_t)sg * 512 + j] = acc[mm][nn][i] + bval;
      }
    }
}

extern "C" void kernel_launch(void* const* d_in, const int* in_sizes, int n_in,
                              void* d_out, int out_size, void* d_ws, size_t ws_size,
                              hipStream_t stream)
{
  const float* query = (const float*)d_in[0];
  const float* key   = (const float*)d_in[1];
  const float* value = (const float*)d_in[2];
  const int*   mask  = (const int*)d_in[3];
  const float* wq  = (const float*)d_in[4];  const float* bq  = (const float*)d_in[5];
  const float* wk  = (const float*)d_in[6];  const float* bk  = (const float*)d_in[7];
  const float* wv  = (const float*)d_in[8];  const float* bv  = (const float*)d_in[9];
  const float* wq1 = (const float*)d_in[10]; const float* bq1 = (const float*)d_in[11];
  const float* wk1 = (const float*)d_in[12]; const float* bk1 = (const float*)d_in[13];
  const float* wfc = (const float*)d_in[14]; const float* bfc = (const float*)d_in[15];

  u16* ws  = (u16*)d_ws;
  u16* Qh  = ws;
  u16* Kh  = Qh  + 8388608;
  u16* Vt  = Kh  + 8388608;
  u16* Q1h = Vt  + 8388608;
  u16* K1h = Q1h + 8388608;
  u16* xa  = K1h + 8388608;
  u16* wts = xa  + 8388608;           // 6 * 262144 u16
  u16* U   = wts + 6 * 262144;        // 134217728 u16 = 268 MB (split path only)
  float* rsum = (float*)(U + 134217728);  // 131072 f32

  const size_t need_split = (size_t)(51904512 + 134217728) * 2 + 524288;  // ~373 MB

  float* outx = (float*)d_out;
  float* ratt = outx + 8388608;

  k_wt6<<<dim3(1024, 6), dim3(256), 0, stream>>>(wq, wk, wv, wq1, wk1, wfc, wts);

  k_proj3<<<dim3(128, 4, 3), dim3(256), 0, stream>>>(
      query, key, value, wts, bq, bk, bv, bq1, bk1, Qh, Kh, Vt, Q1h, K1h);

  (void)hipFuncSetAttribute((const void*)k_pvr,
                            hipFuncAttributeMaxDynamicSharedMemorySize, 49152);
  k_qk<<<dim3(16, 8, 4), dim3(1024), 0, stream>>>(
      Qh, Kh, Q1h, K1h, mask, U, rsum);
  k_pvr<<<dim3(16, 32), dim3(512), 49152, stream>>>(
      U, rsum, Vt, xa, ratt);

  k_fc<<<dim3(128, 4), dim3(256), 0, stream>>>(
      xa, wts + 5 * 262144, bfc, outx);
}

// Round 19
// 406.264 us; speedup vs baseline: 1.0893x; 1.0893x over previous
//
#include <hip/hip_runtime.h>
#include <hip/hip_bf16.h>

typedef unsigned short u16;
typedef unsigned int u32;
typedef unsigned long long u64;
typedef __attribute__((ext_vector_type(8))) short short8;
typedef __attribute__((ext_vector_type(4))) float floatx4;

#define MFMA16(a,b,c) __builtin_amdgcn_mfma_f32_16x16x32_bf16((a),(b),(c),0,0,0)

__device__ __forceinline__ u16 f2bf(float f){
  u32 x = __float_as_uint(f);
  x += 0x7FFFu + ((x >> 16) & 1u);
  return (u16)(x >> 16);
}
__device__ __forceinline__ float frcp(float x){ return __builtin_amdgcn_rcpf(x); }
__device__ __forceinline__ float fexp2(float x){ return __builtin_amdgcn_exp2f(x); }
// 0.125 * log2(e): scale folded into the exp2 argument
#define KEXP 0.18033688011112042f
#define Z4 ((floatx4){0.f,0.f,0.f,0.f})

// async global->LDS 16B per lane: LDS dest = wave-uniform base + lane*16,
// global src is per-lane (pre-swizzled source pattern).
__device__ __forceinline__ void gl_lds16(const u16* src, u16* dst){
  __builtin_amdgcn_global_load_lds(
      (const __attribute__((address_space(1))) unsigned int*)(u64)(src),
      (__attribute__((address_space(3))) unsigned int*)(u32)(u64)(dst),
      16, 0, 0);
}

// ---------------- weight transpose+convert via LDS tiles -----------------------------
// Old k_wt6 read w[d*512+j] with j SLOW across threads -> 2KB-stride uncoalesced reads
// (~16x line amplification on 6 MB). 64x64 tile transpose through LDS: coalesced f32
// reads (j fast), coalesced bf16 writes (d fast). T[64][66]: write 2-way (free),
// read broadcast (free).
__global__ __launch_bounds__(256) void k_wt6(
    const float* __restrict__ w0, const float* __restrict__ w1, const float* __restrict__ w2,
    const float* __restrict__ w3, const float* __restrict__ w4, const float* __restrict__ w5,
    u16* __restrict__ wts)
{
  __shared__ u16 T[64][66];
  const int z = blockIdx.z;
  const float* w;
  switch (z){ case 0: w = w0; break; case 1: w = w1; break; case 2: w = w2; break;
              case 3: w = w3; break; case 4: w = w4; break; default: w = w5; break; }
  const int j0 = blockIdx.x * 64, d0 = blockIdx.y * 64;
  const int c = threadIdx.x & 63, r = threadIdx.x >> 6;
  #pragma unroll
  for (int it = 0; it < 16; ++it){
    const int rr = it * 4 + r;                 // local d
    T[c][rr] = f2bf(w[(size_t)(d0 + rr) * 512 + j0 + c]);
  }
  __syncthreads();
  u16* out = wts + (size_t)z * 262144;
  #pragma unroll
  for (int it = 0; it < 16; ++it){
    const int jr = it * 4 + r;                 // local j
    out[(size_t)(j0 + jr) * 512 + d0 + c] = T[jr][c];
  }
}

// ---------------- 5-way projection GEMM, 128x128 tile (R14-proven) ----------------
// (k_proj3's dual-acc fusion hit 276 unified regs -> 1 wave/SIMD, 196 us. Reverted.)
__global__ __launch_bounds__(256) void k_proj(
    const float* __restrict__ xq, const float* __restrict__ xk, const float* __restrict__ xv,
    const u16* __restrict__ wts,
    const float* __restrict__ bq, const float* __restrict__ bk, const float* __restrict__ bv,
    const float* __restrict__ bq1, const float* __restrict__ bk1,
    u16* __restrict__ Qh, u16* __restrict__ Kh, u16* __restrict__ Vt,
    u16* __restrict__ Q1h, u16* __restrict__ K1h)
{
  __shared__ __align__(16) u16 As[128][72];
  __shared__ __align__(16) u16 Bs[128 * 64];
  int z = blockIdx.z;
  const float* x; const float* bias; u16* out; int vtm = 0;
  switch (z){
    case 0: x = xq; bias = bq;  out = Qh;  break;
    case 1: x = xk; bias = bk;  out = Kh;  break;
    case 2: x = xv; bias = bv;  out = Vt;  vtm = 1; break;
    case 3: x = xq; bias = bq1; out = Q1h; break;
    default: x = xk; bias = bk1; out = K1h; break;
  }
  const u16* wt = wts + (size_t)z * 262144;
  const int tid = threadIdx.x, lane = tid & 63, wid = tid >> 6;
  const int wm = wid >> 1, wn = wid & 1;
  const int m0 = blockIdx.x * 128, n0 = blockIdx.y * 128;
  const int arow = lane & 15, kg = lane >> 4;
  const int ar = tid >> 1, ah = (tid & 1) * 32;
  const int br = tid >> 3, bc = tid & 7;
  u16* const bdst = Bs + wid * 512;

  floatx4 acc[4][4];
  #pragma unroll
  for (int i = 0; i < 4; ++i)
    #pragma unroll
    for (int j = 0; j < 4; ++j) acc[i][j] = Z4;

  for (int k0 = 0; k0 < 512; k0 += 64){
    #pragma unroll
    for (int q = 0; q < 4; ++q)
      gl_lds16(wt + (size_t)(n0 + q * 32 + br) * 512 + k0 + ((bc ^ (br & 7)) * 8),
               bdst + q * 2048);
    const float4* xp = (const float4*)(x + (size_t)(m0 + ar) * 512 + k0 + ah);
    #pragma unroll
    for (int j = 0; j < 4; ++j){
      float4 f0 = xp[2 * j], f1 = xp[2 * j + 1];
      short8 v;
      v[0] = (short)f2bf(f0.x); v[1] = (short)f2bf(f0.y);
      v[2] = (short)f2bf(f0.z); v[3] = (short)f2bf(f0.w);
      v[4] = (short)f2bf(f1.x); v[5] = (short)f2bf(f1.y);
      v[6] = (short)f2bf(f1.z); v[7] = (short)f2bf(f1.w);
      *(short8*)&As[ar][ah + j * 8] = v;
    }
    __syncthreads();
    #pragma unroll
    for (int kk = 0; kk < 2; ++kk){
      short8 af[4], bf[4];
      #pragma unroll
      for (int mm = 0; mm < 4; ++mm)
        af[mm] = *(const short8*)&As[wm * 64 + mm * 16 + arow][kk * 32 + kg * 8];
      #pragma unroll
      for (int nn = 0; nn < 4; ++nn){
        int rr = wn * 64 + nn * 16 + arow;
        bf[nn] = *(const short8*)&Bs[rr * 64 + ((kk * 32 + kg * 8) ^ ((rr & 7) * 8))];
      }
      #pragma unroll
      for (int mm = 0; mm < 4; ++mm)
        #pragma unroll
        for (int nn = 0; nn < 4; ++nn)
          acc[mm][nn] = MFMA16(af[mm], bf[nn], acc[mm][nn]);
    }
    __syncthreads();
  }
  #pragma unroll
  for (int mm = 0; mm < 4; ++mm)
    #pragma unroll
    for (int nn = 0; nn < 4; ++nn){
      int j = n0 + wn * 64 + nn * 16 + arow;
      int h = j >> 6, dh = j & 63;
      float bval = bias[j];
      #pragma unroll
      for (int i = 0; i < 4; ++i){
        int sg = m0 + wm * 64 + mm * 16 + kg * 4 + i;
        int bb = sg >> 10, s = sg & 1023;
        float val = acc[mm][nn][i] + bval;
        size_t o = vtm ? (((size_t)((bb << 3) + h) * 64 + dh) * 1024 + s)
                       : (((size_t)((bb << 3) + h) * 1024 + s) * 64 + dh);
        out[o] = f2bf(val);
      }
    }
}

// ================= SPLIT PATH =================
// ---------------- kernel A (R17-proven): k-outer / q-inner dual-QK -> U, rsum --------
__global__ void __launch_bounds__(1024)
k_qk(const u16* __restrict__ Qh, const u16* __restrict__ Kh,
     const u16* __restrict__ Q1h, const u16* __restrict__ K1h,
     const int* __restrict__ mask, u16* __restrict__ U, float* __restrict__ rsum)
{
  __shared__ __align__(16) u16 stg[2 * 8192];

  const int tid = threadIdx.x, lane = tid & 63, wid = tid >> 6;
  const int arow = lane & 15, kg = lane >> 4;
  const int b = blockIdx.x, h = blockIdx.y, qs = blockIdx.z;
  const size_t hb = (size_t)(b * 8 + h);

  const int qrow = qs * 256 + wid * 16 + arow;
  const u16* qp  = Qh  + (hb * 1024 + qrow) * 64 + kg * 8;
  const u16* q1p = Q1h + (hb * 1024 + qrow) * 64 + kg * 8;
  short8 aq0 = *(const short8*)qp,  aq1 = *(const short8*)(qp + 32);
  short8 ap0 = *(const short8*)q1p, ap1 = *(const short8*)(q1p + 32);

  u64 mb = 0;
  #pragma unroll
  for (int t = 0; t < 16; ++t)
    #pragma unroll
    for (int cs = 0; cs < 4; ++cs)
      mb |= (mask[b * 1024 + t * 64 + cs * 16 + arow] != 0 ? 1ull : 0ull) << (t * 4 + cs);

  const int ls_half = tid >> 9;
  const int ls_r = (tid & 511) >> 3;
  const int ls_c = (tid & 7) ^ (ls_r & 7);
  u16* const sbase = stg + wid * 512;
  const u16* lsrc = (ls_half ? Kh : K1h) + hb * 65536 + (size_t)ls_r * 64 + ls_c * 8;

  u16* const ubase = U + hb * 1048576;
  const int urow0 = qs * 256 + wid * 16 + kg * 4;

  gl_lds16(lsrc, sbase);
  __syncthreads();

  float sacc[4] = {0.f, 0.f, 0.f, 0.f};
  for (int t = 0; t < 16; ++t){
    if (t < 15)
      gl_lds16(lsrc + (size_t)(t + 1) * 4096, sbase + (((t + 1) & 1) << 13));
    const u16* kb = stg + ((t & 1) << 13);
    #pragma unroll
    for (int cs = 0; cs < 4; ++cs){
      const int krow = cs * 16 + arow;
      const int swl = (krow & 7) * 8;
      short8 b1a = *(const short8*)&kb[krow * 64 + ((     kg * 8) ^ swl)];
      short8 b1b = *(const short8*)&kb[krow * 64 + ((32 + kg * 8) ^ swl)];
      short8 bea = *(const short8*)&kb[4096 + krow * 64 + ((     kg * 8) ^ swl)];
      short8 beb = *(const short8*)&kb[4096 + krow * 64 + ((32 + kg * 8) ^ swl)];
      floatx4 cg4 = Z4, ce4 = Z4;
      cg4 = MFMA16(ap0, b1a, cg4); cg4 = MFMA16(ap1, b1b, cg4);
      ce4 = MFMA16(aq0, bea, ce4); ce4 = MFMA16(aq1, beb, ce4);
      const float msk = ((mb >> (t * 4 + cs)) & 1ull) ? 1.0f : 0.0f;
      #pragma unroll
      for (int i = 0; i < 4; ++i){
        float p = fexp2(ce4[i] * KEXP) * msk;
        float g = frcp(1.0f + fexp2(-cg4[i] * KEXP));
        sacc[i] += p;
        ubase[(size_t)(urow0 + i) * 1024 + t * 64 + cs * 16 + arow] = f2bf(p * g);
      }
    }
    __syncthreads();
  }

  #pragma unroll
  for (int i = 0; i < 4; ++i){
    #pragma unroll
    for (int off = 1; off <= 8; off <<= 1)
      sacc[i] += __shfl_xor(sacc[i], off, 64);
  }
  if (arow == 0){
    #pragma unroll
    for (int i = 0; i < 4; ++i)
      rsum[hb * 1024 + urow0 + i] = sacc[i];
  }
}

// ---------------- kernel B (R16-proven, 173 us): r_att + PV from STAGED U ------------
__global__ void __launch_bounds__(512)
__attribute__((amdgpu_waves_per_eu(4, 4)))
k_pvr(const u16* __restrict__ U, const float* __restrict__ rsum,
      const u16* __restrict__ Vt, u16* __restrict__ xa, float* __restrict__ ratt)
{
  extern __shared__ __align__(16) u16 stg2[];   // 2 bufs x 12288 u16: U[0,4096) V[4096,12288)

  const int tid = threadIdx.x, lane = tid & 63, wid = tid >> 6;
  const int arow = lane & 15, kg = lane >> 4;
  const int b = blockIdx.x, qt = blockIdx.y;
  const int s2 = wid & 1, cg = wid >> 1;
  const int cres = cg * 16 + arow;
  const int wrow = wid * 4;
  const int a_r = s2 * 16 + arow;

  const int ur = tid >> 4, uc = (tid & 15) ^ (ur & 7);
  const int vr0 = tid >> 4, vc0 = (tid & 15) ^ (vr0 & 7);
  const int vr1 = vr0 + 32, vc1 = (tid & 15) ^ (vr1 & 7);

  float racc[4][16];
  #pragma unroll
  for (int r = 0; r < 4; ++r)
    #pragma unroll
    for (int j = 0; j < 16; ++j) racc[r][j] = 0.f;

  for (int h = 0; h < 8; ++h){
    const size_t hb = (size_t)(b * 8 + h);
    const u16* ub = U  + hb * 1048576 + (size_t)(qt * 32) * 1024;
    const u16* vb = Vt + hb * 65536;

    float rlh[4], rlx[4];
    #pragma unroll
    for (int r = 0; r < 4; ++r)
      rlh[r] = frcp(rsum[hb * 1024 + qt * 32 + wrow + r]) * 0.125f;
    #pragma unroll
    for (int i = 0; i < 4; ++i)
      rlx[i] = frcp(rsum[hb * 1024 + qt * 32 + s2 * 16 + kg * 4 + i]);

    gl_lds16(ub + (size_t)ur * 1024 + uc * 8,  stg2 + tid * 8);
    gl_lds16(vb + (size_t)vr0 * 1024 + vc0 * 8, stg2 + 4096 + tid * 8);
    gl_lds16(vb + (size_t)vr1 * 1024 + vc1 * 8, stg2 + 8192 + tid * 8);
    __syncthreads();

    floatx4 cpv = Z4;
    for (int t = 0; t < 8; ++t){
      if (t < 7){
        const int nb = ((t + 1) & 1) * 12288;
        gl_lds16(ub + (size_t)ur * 1024 + (t + 1) * 128 + uc * 8,  stg2 + nb + tid * 8);
        gl_lds16(vb + (size_t)vr0 * 1024 + (t + 1) * 128 + vc0 * 8, stg2 + nb + 4096 + tid * 8);
        gl_lds16(vb + (size_t)vr1 * 1024 + (t + 1) * 128 + vc1 * 8, stg2 + nb + 8192 + tid * 8);
      }
      const u16* Ut  = stg2 + (t & 1) * 12288;
      const u16* Vts = Ut + 4096;
      #pragma unroll
      for (int r = 0; r < 4; ++r){
        const int row = wrow + r;
        u32 w = *(const u32*)&Ut[row * 128 + ((lane * 2) ^ ((row & 7) * 8))];
        racc[r][2 * t]     += __uint_as_float(w << 16) * rlh[r];
        racc[r][2 * t + 1] += __uint_as_float(w & 0xFFFF0000u) * rlh[r];
      }
      #pragma unroll
      for (int ks = 0; ks < 4; ++ks){
        short8 a  = *(const short8*)&Ut[a_r * 128 + ((ks * 32 + kg * 8) ^ ((a_r & 7) * 8))];
        short8 bv = *(const short8*)&Vts[cres * 128 + ((ks * 32 + kg * 8) ^ ((cres & 7) * 8))];
        cpv = MFMA16(a, bv, cpv);
      }
      __syncthreads();
    }
    #pragma unroll
    for (int i = 0; i < 4; ++i){
      const int g = qt * 32 + s2 * 16 + kg * 4 + i;
      xa[((size_t)(b * 1024 + g)) * 512 + h * 64 + cres] = f2bf(cpv[i] * rlx[i]);
    }
  }

  #pragma unroll
  for (int r = 0; r < 4; ++r){
    const size_t rb = ((size_t)(b * 1024 + qt * 32 + wrow + r)) * 1024;
    #pragma unroll
    for (int j = 0; j < 8; ++j){
      float2 v = {racc[r][2 * j], racc[r][2 * j + 1]};
      *(float2*)&ratt[rb + j * 128 + lane * 2] = v;
    }
  }
}

// ---------------- final FC, 128x128 tile (R14-proven) ----------------
__global__ __launch_bounds__(256) void k_fc(
    const u16* __restrict__ xa, const u16* __restrict__ wt,
    const float* __restrict__ bias, float* __restrict__ out)
{
  __shared__ __align__(16) u16 Asf[128 * 64];
  __shared__ __align__(16) u16 Bsf[128 * 64];
  const int tid = threadIdx.x, lane = tid & 63, wid = tid >> 6;
  const int wm = wid >> 1, wn = wid & 1;
  const int m0 = blockIdx.x * 128, n0 = blockIdx.y * 128;
  const int arow = lane & 15, kg = lane >> 4;
  const int br = tid >> 3, bc = tid & 7;
  u16* const adst = Asf + wid * 512;
  u16* const bdst = Bsf + wid * 512;

  floatx4 acc[4][4];
  #pragma unroll
  for (int i = 0; i < 4; ++i)
    #pragma unroll
    for (int j = 0; j < 4; ++j) acc[i][j] = Z4;

  for (int k0 = 0; k0 < 512; k0 += 64){
    #pragma unroll
    for (int q = 0; q < 4; ++q){
      gl_lds16(xa + (size_t)(m0 + q * 32 + br) * 512 + k0 + ((bc ^ (br & 7)) * 8),
               adst + q * 2048);
      gl_lds16(wt + (size_t)(n0 + q * 32 + br) * 512 + k0 + ((bc ^ (br & 7)) * 8),
               bdst + q * 2048);
    }
    __syncthreads();
    #pragma unroll
    for (int kk = 0; kk < 2; ++kk){
      short8 af[4], bf[4];
      #pragma unroll
      for (int mm = 0; mm < 4; ++mm){
        int rr = wm * 64 + mm * 16 + arow;
        af[mm] = *(const short8*)&Asf[rr * 64 + ((kk * 32 + kg * 8) ^ ((rr & 7) * 8))];
      }
      #pragma unroll
      for (int nn = 0; nn < 4; ++nn){
        int rr = wn * 64 + nn * 16 + arow;
        bf[nn] = *(const short8*)&Bsf[rr * 64 + ((kk * 32 + kg * 8) ^ ((rr & 7) * 8))];
      }
      #pragma unroll
      for (int mm = 0; mm < 4; ++mm)
        #pragma unroll
        for (int nn = 0; nn < 4; ++nn)
          acc[mm][nn] = MFMA16(af[mm], bf[nn], acc[mm][nn]);
    }
    __syncthreads();
  }
  #pragma unroll
  for (int mm = 0; mm < 4; ++mm)
    #pragma unroll
    for (int nn = 0; nn < 4; ++nn){
      int j = n0 + wn * 64 + nn * 16 + arow;
      float bval = bias[j];
      #pragma unroll
      for (int i = 0; i < 4; ++i){
        int sg = m0 + wm * 64 + mm * 16 + kg * 4 + i;
        out[(size_t)sg * 512 + j] = acc[mm][nn][i] + bval;
      }
    }
}

extern "C" void kernel_launch(void* const* d_in, const int* in_sizes, int n_in,
                              void* d_out, int out_size, void* d_ws, size_t ws_size,
                              hipStream_t stream)
{
  const float* query = (const float*)d_in[0];
  const float* key   = (const float*)d_in[1];
  const float* value = (const float*)d_in[2];
  const int*   mask  = (const int*)d_in[3];
  const float* wq  = (const float*)d_in[4];  const float* bq  = (const float*)d_in[5];
  const float* wk  = (const float*)d_in[6];  const float* bk  = (const float*)d_in[7];
  const float* wv  = (const float*)d_in[8];  const float* bv  = (const float*)d_in[9];
  const float* wq1 = (const float*)d_in[10]; const float* bq1 = (const float*)d_in[11];
  const float* wk1 = (const float*)d_in[12]; const float* bk1 = (const float*)d_in[13];
  const float* wfc = (const float*)d_in[14]; const float* bfc = (const float*)d_in[15];

  u16* ws  = (u16*)d_ws;
  u16* Qh  = ws;
  u16* Kh  = Qh  + 8388608;
  u16* Vt  = Kh  + 8388608;
  u16* Q1h = Vt  + 8388608;
  u16* K1h = Q1h + 8388608;
  u16* xa  = K1h + 8388608;
  u16* wts = xa  + 8388608;           // 6 * 262144 u16
  u16* U   = wts + 6 * 262144;        // 134217728 u16 = 268 MB
  float* rsum = (float*)(U + 134217728);  // 131072 f32

  float* outx = (float*)d_out;
  float* ratt = outx + 8388608;

  k_wt6<<<dim3(8, 8, 6), dim3(256), 0, stream>>>(wq, wk, wv, wq1, wk1, wfc, wts);

  k_proj<<<dim3(128, 4, 5), dim3(256), 0, stream>>>(
      query, key, value, wts, bq, bk, bv, bq1, bk1, Qh, Kh, Vt, Q1h, K1h);

  (void)hipFuncSetAttribute((const void*)k_pvr,
                            hipFuncAttributeMaxDynamicSharedMemorySize, 49152);
  k_qk<<<dim3(16, 8, 4), dim3(1024), 0, stream>>>(
      Qh, Kh, Q1h, K1h, mask, U, rsum);
  k_pvr<<<dim3(16, 32), dim3(512), 49152, stream>>>(
      U, rsum, Vt, xa, ratt);

  k_fc<<<dim3(128, 4), dim3(256), 0, stream>>>(
      xa, wts + 5 * 262144, bfc, outx);
}

// Round 20
// 391.797 us; speedup vs baseline: 1.1295x; 1.0369x over previous
//
#include <hip/hip_runtime.h>
#include <hip/hip_bf16.h>

typedef unsigned short u16;
typedef unsigned int u32;
typedef unsigned long long u64;
typedef __attribute__((ext_vector_type(8))) short short8;
typedef __attribute__((ext_vector_type(4))) float floatx4;

#define MFMA16(a,b,c) __builtin_amdgcn_mfma_f32_16x16x32_bf16((a),(b),(c),0,0,0)

__device__ __forceinline__ u16 f2bf(float f){
  u32 x = __float_as_uint(f);
  x += 0x7FFFu + ((x >> 16) & 1u);
  return (u16)(x >> 16);
}
__device__ __forceinline__ float frcp(float x){ return __builtin_amdgcn_rcpf(x); }
__device__ __forceinline__ float fexp2(float x){ return __builtin_amdgcn_exp2f(x); }
// 0.125 * log2(e): scale folded into the exp2 argument
#define KEXP 0.18033688011112042f
#define Z4 ((floatx4){0.f,0.f,0.f,0.f})

// async global->LDS 16B per lane: LDS dest = wave-uniform base + lane*16,
// global src is per-lane (pre-swizzled source pattern).
__device__ __forceinline__ void gl_lds16(const u16* src, u16* dst){
  __builtin_amdgcn_global_load_lds(
      (const __attribute__((address_space(1))) unsigned int*)(u64)(src),
      (__attribute__((address_space(3))) unsigned int*)(u32)(u64)(dst),
      16, 0, 0);
}

// ---------------- weight transpose+convert via LDS tiles (R19-proven) ----------------
__global__ __launch_bounds__(256) void k_wt6(
    const float* __restrict__ w0, const float* __restrict__ w1, const float* __restrict__ w2,
    const float* __restrict__ w3, const float* __restrict__ w4, const float* __restrict__ w5,
    u16* __restrict__ wts)
{
  __shared__ u16 T[64][66];
  const int z = blockIdx.z;
  const float* w;
  switch (z){ case 0: w = w0; break; case 1: w = w1; break; case 2: w = w2; break;
              case 3: w = w3; break; case 4: w = w4; break; default: w = w5; break; }
  const int j0 = blockIdx.x * 64, d0 = blockIdx.y * 64;
  const int c = threadIdx.x & 63, r = threadIdx.x >> 6;
  #pragma unroll
  for (int it = 0; it < 16; ++it){
    const int rr = it * 4 + r;
    T[c][rr] = f2bf(w[(size_t)(d0 + rr) * 512 + j0 + c]);
  }
  __syncthreads();
  u16* out = wts + (size_t)z * 262144;
  #pragma unroll
  for (int it = 0; it < 16; ++it){
    const int jr = it * 4 + r;
    out[(size_t)(j0 + jr) * 512 + d0 + c] = T[jr][c];
  }
}

// ---------------- 5-way projection GEMM, 128x128 tile (R14-proven) ----------------
__global__ __launch_bounds__(256) void k_proj(
    const float* __restrict__ xq, const float* __restrict__ xk, const float* __restrict__ xv,
    const u16* __restrict__ wts,
    const float* __restrict__ bq, const float* __restrict__ bk, const float* __restrict__ bv,
    const float* __restrict__ bq1, const float* __restrict__ bk1,
    u16* __restrict__ Qh, u16* __restrict__ Kh, u16* __restrict__ Vt,
    u16* __restrict__ Q1h, u16* __restrict__ K1h)
{
  __shared__ __align__(16) u16 As[128][72];
  __shared__ __align__(16) u16 Bs[128 * 64];
  int z = blockIdx.z;
  const float* x; const float* bias; u16* out; int vtm = 0;
  switch (z){
    case 0: x = xq; bias = bq;  out = Qh;  break;
    case 1: x = xk; bias = bk;  out = Kh;  break;
    case 2: x = xv; bias = bv;  out = Vt;  vtm = 1; break;
    case 3: x = xq; bias = bq1; out = Q1h; break;
    default: x = xk; bias = bk1; out = K1h; break;
  }
  const u16* wt = wts + (size_t)z * 262144;
  const int tid = threadIdx.x, lane = tid & 63, wid = tid >> 6;
  const int wm = wid >> 1, wn = wid & 1;
  const int m0 = blockIdx.x * 128, n0 = blockIdx.y * 128;
  const int arow = lane & 15, kg = lane >> 4;
  const int ar = tid >> 1, ah = (tid & 1) * 32;
  const int br = tid >> 3, bc = tid & 7;
  u16* const bdst = Bs + wid * 512;

  floatx4 acc[4][4];
  #pragma unroll
  for (int i = 0; i < 4; ++i)
    #pragma unroll
    for (int j = 0; j < 4; ++j) acc[i][j] = Z4;

  for (int k0 = 0; k0 < 512; k0 += 64){
    #pragma unroll
    for (int q = 0; q < 4; ++q)
      gl_lds16(wt + (size_t)(n0 + q * 32 + br) * 512 + k0 + ((bc ^ (br & 7)) * 8),
               bdst + q * 2048);
    const float4* xp = (const float4*)(x + (size_t)(m0 + ar) * 512 + k0 + ah);
    #pragma unroll
    for (int j = 0; j < 4; ++j){
      float4 f0 = xp[2 * j], f1 = xp[2 * j + 1];
      short8 v;
      v[0] = (short)f2bf(f0.x); v[1] = (short)f2bf(f0.y);
      v[2] = (short)f2bf(f0.z); v[3] = (short)f2bf(f0.w);
      v[4] = (short)f2bf(f1.x); v[5] = (short)f2bf(f1.y);
      v[6] = (short)f2bf(f1.z); v[7] = (short)f2bf(f1.w);
      *(short8*)&As[ar][ah + j * 8] = v;
    }
    __syncthreads();
    #pragma unroll
    for (int kk = 0; kk < 2; ++kk){
      short8 af[4], bf[4];
      #pragma unroll
      for (int mm = 0; mm < 4; ++mm)
        af[mm] = *(const short8*)&As[wm * 64 + mm * 16 + arow][kk * 32 + kg * 8];
      #pragma unroll
      for (int nn = 0; nn < 4; ++nn){
        int rr = wn * 64 + nn * 16 + arow;
        bf[nn] = *(const short8*)&Bs[rr * 64 + ((kk * 32 + kg * 8) ^ ((rr & 7) * 8))];
      }
      #pragma unroll
      for (int mm = 0; mm < 4; ++mm)
        #pragma unroll
        for (int nn = 0; nn < 4; ++nn)
          acc[mm][nn] = MFMA16(af[mm], bf[nn], acc[mm][nn]);
    }
    __syncthreads();
  }
  #pragma unroll
  for (int mm = 0; mm < 4; ++mm)
    #pragma unroll
    for (int nn = 0; nn < 4; ++nn){
      int j = n0 + wn * 64 + nn * 16 + arow;
      int h = j >> 6, dh = j & 63;
      float bval = bias[j];
      #pragma unroll
      for (int i = 0; i < 4; ++i){
        int sg = m0 + wm * 64 + mm * 16 + kg * 4 + i;
        int bb = sg >> 10, s = sg & 1023;
        float val = acc[mm][nn][i] + bval;
        size_t o = vtm ? (((size_t)((bb << 3) + h) * 64 + dh) * 1024 + s)
                       : (((size_t)((bb << 3) + h) * 1024 + s) * 64 + dh);
        out[o] = f2bf(val);
      }
    }
}

// ================= SPLIT PATH =================
// ---------------- kernel A (R17-proven): k-outer / q-inner dual-QK -> U, rsum --------
__global__ void __launch_bounds__(1024)
k_qk(const u16* __restrict__ Qh, const u16* __restrict__ Kh,
     const u16* __restrict__ Q1h, const u16* __restrict__ K1h,
     const int* __restrict__ mask, u16* __restrict__ U, float* __restrict__ rsum)
{
  __shared__ __align__(16) u16 stg[2 * 8192];

  const int tid = threadIdx.x, lane = tid & 63, wid = tid >> 6;
  const int arow = lane & 15, kg = lane >> 4;
  const int b = blockIdx.x, h = blockIdx.y, qs = blockIdx.z;
  const size_t hb = (size_t)(b * 8 + h);

  const int qrow = qs * 256 + wid * 16 + arow;
  const u16* qp  = Qh  + (hb * 1024 + qrow) * 64 + kg * 8;
  const u16* q1p = Q1h + (hb * 1024 + qrow) * 64 + kg * 8;
  short8 aq0 = *(const short8*)qp,  aq1 = *(const short8*)(qp + 32);
  short8 ap0 = *(const short8*)q1p, ap1 = *(const short8*)(q1p + 32);

  u64 mb = 0;
  #pragma unroll
  for (int t = 0; t < 16; ++t)
    #pragma unroll
    for (int cs = 0; cs < 4; ++cs)
      mb |= (mask[b * 1024 + t * 64 + cs * 16 + arow] != 0 ? 1ull : 0ull) << (t * 4 + cs);

  const int ls_half = tid >> 9;
  const int ls_r = (tid & 511) >> 3;
  const int ls_c = (tid & 7) ^ (ls_r & 7);
  u16* const sbase = stg + wid * 512;
  const u16* lsrc = (ls_half ? Kh : K1h) + hb * 65536 + (size_t)ls_r * 64 + ls_c * 8;

  u16* const ubase = U + hb * 1048576;
  const int urow0 = qs * 256 + wid * 16 + kg * 4;

  gl_lds16(lsrc, sbase);
  __syncthreads();

  float sacc[4] = {0.f, 0.f, 0.f, 0.f};
  for (int t = 0; t < 16; ++t){
    if (t < 15)
      gl_lds16(lsrc + (size_t)(t + 1) * 4096, sbase + (((t + 1) & 1) << 13));
    const u16* kb = stg + ((t & 1) << 13);
    #pragma unroll
    for (int cs = 0; cs < 4; ++cs){
      const int krow = cs * 16 + arow;
      const int swl = (krow & 7) * 8;
      short8 b1a = *(const short8*)&kb[krow * 64 + ((     kg * 8) ^ swl)];
      short8 b1b = *(const short8*)&kb[krow * 64 + ((32 + kg * 8) ^ swl)];
      short8 bea = *(const short8*)&kb[4096 + krow * 64 + ((     kg * 8) ^ swl)];
      short8 beb = *(const short8*)&kb[4096 + krow * 64 + ((32 + kg * 8) ^ swl)];
      floatx4 cg4 = Z4, ce4 = Z4;
      cg4 = MFMA16(ap0, b1a, cg4); cg4 = MFMA16(ap1, b1b, cg4);
      ce4 = MFMA16(aq0, bea, ce4); ce4 = MFMA16(aq1, beb, ce4);
      const float msk = ((mb >> (t * 4 + cs)) & 1ull) ? 1.0f : 0.0f;
      #pragma unroll
      for (int i = 0; i < 4; ++i){
        float p = fexp2(ce4[i] * KEXP) * msk;
        float g = frcp(1.0f + fexp2(-cg4[i] * KEXP));
        sacc[i] += p;
        ubase[(size_t)(urow0 + i) * 1024 + t * 64 + cs * 16 + arow] = f2bf(p * g);
      }
    }
    __syncthreads();
  }

  #pragma unroll
  for (int i = 0; i < 4; ++i){
    #pragma unroll
    for (int off = 1; off <= 8; off <<= 1)
      sacc[i] += __shfl_xor(sacc[i], off, 64);
  }
  if (arow == 0){
    #pragma unroll
    for (int i = 0; i < 4; ++i)
      rsum[hb * 1024 + urow0 + i] = sacc[i];
  }
}

// ---------------- kernel B v4: 64-row blocks, r_att + PV from STAGED U ---------------
// grid (16 b, 16 qt of 64 rows); 1024 thr (16 waves); LDS 64 KB dbuf x {U 16KB, V 16KB}
// -> 1 block/CU. V staging amortized over 64 rows (was 32): per-CU DMA -33%, MFMA per
// staged KB 2x. Same proven dbuf + __syncthreads loop as R16.
__global__ void __launch_bounds__(1024)
__attribute__((amdgpu_waves_per_eu(4, 4)))
k_pvr(const u16* __restrict__ U, const float* __restrict__ rsum,
      const u16* __restrict__ Vt, u16* __restrict__ xa, float* __restrict__ ratt)
{
  extern __shared__ __align__(16) u16 stg2[];   // 2 bufs x 16384 u16: U[0,8192) V[8192,16384)

  const int tid = threadIdx.x, lane = tid & 63, wid = tid >> 6;
  const int arow = lane & 15, kg = lane >> 4;
  const int b = blockIdx.x, qt = blockIdx.y;
  const int rs = wid & 3, cs2 = wid >> 2;   // row strip (16) x dh col group (16)
  const int cres = cs2 * 16 + arow;         // dh residue 0..63
  const int wrow = wid * 4;                 // racc rows (16 waves x 4 = 64)
  const int a_r = rs * 16 + arow;           // PV A row in U tile

  // staging map (both tiles 64x128): row ur 0..63, swizzled 16B chunk
  const int ur = tid >> 4, uc = (tid & 15) ^ (ur & 7);

  float racc[4][16];
  #pragma unroll
  for (int r = 0; r < 4; ++r)
    #pragma unroll
    for (int j = 0; j < 16; ++j) racc[r][j] = 0.f;

  for (int h = 0; h < 8; ++h){
    const size_t hb = (size_t)(b * 8 + h);
    const u16* ub = U  + hb * 1048576 + (size_t)(qt * 64) * 1024;
    const u16* vb = Vt + hb * 65536;

    float rlh[4], rlx[4];
    #pragma unroll
    for (int r = 0; r < 4; ++r)
      rlh[r] = frcp(rsum[hb * 1024 + qt * 64 + wrow + r]) * 0.125f;
    #pragma unroll
    for (int i = 0; i < 4; ++i)
      rlx[i] = frcp(rsum[hb * 1024 + qt * 64 + rs * 16 + kg * 4 + i]);

    // prologue: stage U t0 + V t0 -> buf 0
    gl_lds16(ub + (size_t)ur * 1024 + uc * 8, stg2 + tid * 8);
    gl_lds16(vb + (size_t)ur * 1024 + uc * 8, stg2 + 8192 + tid * 8);
    __syncthreads();

    floatx4 cpv = Z4;
    for (int t = 0; t < 8; ++t){
      if (t < 7){
        const int nb = ((t + 1) & 1) * 16384;
        gl_lds16(ub + (size_t)ur * 1024 + (t + 1) * 128 + uc * 8, stg2 + nb + tid * 8);
        gl_lds16(vb + (size_t)ur * 1024 + (t + 1) * 128 + uc * 8, stg2 + nb + 8192 + tid * 8);
      }
      const u16* Ut  = stg2 + (t & 1) * 16384;
      const u16* Vts = Ut + 8192;
      // racc from staged U (rows wrow..+3, cols t*128 + lane*2 (+1))
      #pragma unroll
      for (int r = 0; r < 4; ++r){
        const int row = wrow + r;
        u32 w = *(const u32*)&Ut[row * 128 + ((lane * 2) ^ ((row & 7) * 8))];
        racc[r][2 * t]     += __uint_as_float(w << 16) * rlh[r];
        racc[r][2 * t + 1] += __uint_as_float(w & 0xFFFF0000u) * rlh[r];
      }
      // PV MFMA: A rows rs*16.., B dh rows cres; k = t*128 + ks*32
      #pragma unroll
      for (int ks = 0; ks < 4; ++ks){
        short8 a  = *(const short8*)&Ut[a_r * 128 + ((ks * 32 + kg * 8) ^ ((a_r & 7) * 8))];
        short8 bv = *(const short8*)&Vts[cres * 128 + ((ks * 32 + kg * 8) ^ ((cres & 7) * 8))];
        cpv = MFMA16(a, bv, cpv);
      }
      __syncthreads();
    }
    // epilogue: scale by 1/sum, write xa
    #pragma unroll
    for (int i = 0; i < 4; ++i){
      const int g = qt * 64 + rs * 16 + kg * 4 + i;
      xa[((size_t)(b * 1024 + g)) * 512 + h * 64 + cres] = f2bf(cpv[i] * rlx[i]);
    }
  }

  // r_att writeout (float2-coalesced: col = j*128 + lane*2 + par)
  #pragma unroll
  for (int r = 0; r < 4; ++r){
    const size_t rb = ((size_t)(b * 1024 + qt * 64 + wrow + r)) * 1024;
    #pragma unroll
    for (int j = 0; j < 8; ++j){
      float2 v = {racc[r][2 * j], racc[r][2 * j + 1]};
      *(float2*)&ratt[rb + j * 128 + lane * 2] = v;
    }
  }
}

// ---------------- final FC, 128x128 tile (R14-proven) ----------------
__global__ __launch_bounds__(256) void k_fc(
    const u16* __restrict__ xa, const u16* __restrict__ wt,
    const float* __restrict__ bias, float* __restrict__ out)
{
  __shared__ __align__(16) u16 Asf[128 * 64];
  __shared__ __align__(16) u16 Bsf[128 * 64];
  const int tid = threadIdx.x, lane = tid & 63, wid = tid >> 6;
  const int wm = wid >> 1, wn = wid & 1;
  const int m0 = blockIdx.x * 128, n0 = blockIdx.y * 128;
  const int arow = lane & 15, kg = lane >> 4;
  const int br = tid >> 3, bc = tid & 7;
  u16* const adst = Asf + wid * 512;
  u16* const bdst = Bsf + wid * 512;

  floatx4 acc[4][4];
  #pragma unroll
  for (int i = 0; i < 4; ++i)
    #pragma unroll
    for (int j = 0; j < 4; ++j) acc[i][j] = Z4;

  for (int k0 = 0; k0 < 512; k0 += 64){
    #pragma unroll
    for (int q = 0; q < 4; ++q){
      gl_lds16(xa + (size_t)(m0 + q * 32 + br) * 512 + k0 + ((bc ^ (br & 7)) * 8),
               adst + q * 2048);
      gl_lds16(wt + (size_t)(n0 + q * 32 + br) * 512 + k0 + ((bc ^ (br & 7)) * 8),
               bdst + q * 2048);
    }
    __syncthreads();
    #pragma unroll
    for (int kk = 0; kk < 2; ++kk){
      short8 af[4], bf[4];
      #pragma unroll
      for (int mm = 0; mm < 4; ++mm){
        int rr = wm * 64 + mm * 16 + arow;
        af[mm] = *(const short8*)&Asf[rr * 64 + ((kk * 32 + kg * 8) ^ ((rr & 7) * 8))];
      }
      #pragma unroll
      for (int nn = 0; nn < 4; ++nn){
        int rr = wn * 64 + nn * 16 + arow;
        bf[nn] = *(const short8*)&Bsf[rr * 64 + ((kk * 32 + kg * 8) ^ ((rr & 7) * 8))];
      }
      #pragma unroll
      for (int mm = 0; mm < 4; ++mm)
        #pragma unroll
        for (int nn = 0; nn < 4; ++nn)
          acc[mm][nn] = MFMA16(af[mm], bf[nn], acc[mm][nn]);
    }
    __syncthreads();
  }
  #pragma unroll
  for (int mm = 0; mm < 4; ++mm)
    #pragma unroll
    for (int nn = 0; nn < 4; ++nn){
      int j = n0 + wn * 64 + nn * 16 + arow;
      float bval = bias[j];
      #pragma unroll
      for (int i = 0; i < 4; ++i){
        int sg = m0 + wm * 64 + mm * 16 + kg * 4 + i;
        out[(size_t)sg * 512 + j] = acc[mm][nn][i] + bval;
      }
    }
}

extern "C" void kernel_launch(void* const* d_in, const int* in_sizes, int n_in,
                              void* d_out, int out_size, void* d_ws, size_t ws_size,
                              hipStream_t stream)
{
  const float* query = (const float*)d_in[0];
  const float* key   = (const float*)d_in[1];
  const float* value = (const float*)d_in[2];
  const int*   mask  = (const int*)d_in[3];
  const float* wq  = (const float*)d_in[4];  const float* bq  = (const float*)d_in[5];
  const float* wk  = (const float*)d_in[6];  const float* bk  = (const float*)d_in[7];
  const float* wv  = (const float*)d_in[8];  const float* bv  = (const float*)d_in[9];
  const float* wq1 = (const float*)d_in[10]; const float* bq1 = (const float*)d_in[11];
  const float* wk1 = (const float*)d_in[12]; const float* bk1 = (const float*)d_in[13];
  const float* wfc = (const float*)d_in[14]; const float* bfc = (const float*)d_in[15];

  u16* ws  = (u16*)d_ws;
  u16* Qh  = ws;
  u16* Kh  = Qh  + 8388608;
  u16* Vt  = Kh  + 8388608;
  u16* Q1h = Vt  + 8388608;
  u16* K1h = Q1h + 8388608;
  u16* xa  = K1h + 8388608;
  u16* wts = xa  + 8388608;           // 6 * 262144 u16
  u16* U   = wts + 6 * 262144;        // 134217728 u16 = 268 MB
  float* rsum = (float*)(U + 134217728);  // 131072 f32

  float* outx = (float*)d_out;
  float* ratt = outx + 8388608;

  k_wt6<<<dim3(8, 8, 6), dim3(256), 0, stream>>>(wq, wk, wv, wq1, wk1, wfc, wts);

  k_proj<<<dim3(128, 4, 5), dim3(256), 0, stream>>>(
      query, key, value, wts, bq, bk, bv, bq1, bk1, Qh, Kh, Vt, Q1h, K1h);

  (void)hipFuncSetAttribute((const void*)k_pvr,
                            hipFuncAttributeMaxDynamicSharedMemorySize, 65536);
  k_qk<<<dim3(16, 8, 4), dim3(1024), 0, stream>>>(
      Qh, Kh, Q1h, K1h, mask, U, rsum);
  k_pvr<<<dim3(16, 16), dim3(1024), 65536, stream>>>(
      U, rsum, Vt, xa, ratt);

  k_fc<<<dim3(128, 4), dim3(256), 0, stream>>>(
      xa, wts + 5 * 262144, bfc, outx);
}

// Round 22
// 354.614 us; speedup vs baseline: 1.2480x; 1.1049x over previous
//
#include <hip/hip_runtime.h>
#include <hip/hip_bf16.h>

typedef unsigned short u16;
typedef unsigned int u32;
typedef unsigned long long u64;
typedef __attribute__((ext_vector_type(8))) short short8;
typedef __attribute__((ext_vector_type(4))) float floatx4;

#define MFMA16(a,b,c) __builtin_amdgcn_mfma_f32_16x16x32_bf16((a),(b),(c),0,0,0)

__device__ __forceinline__ u16 f2bf(float f){
  u32 x = __float_as_uint(f);
  x += 0x7FFFu + ((x >> 16) & 1u);
  return (u16)(x >> 16);
}
__device__ __forceinline__ float frcp(float x){ return __builtin_amdgcn_rcpf(x); }
__device__ __forceinline__ float fexp2(float x){ return __builtin_amdgcn_exp2f(x); }
// 0.125 * log2(e): scale folded into the exp2 argument
#define KEXP 0.18033688011112042f
#define Z4 ((floatx4){0.f,0.f,0.f,0.f})

// async global->LDS 16B per lane: LDS dest = wave-uniform base + lane*16,
// global src is per-lane (pre-swizzled source pattern).
__device__ __forceinline__ void gl_lds16(const u16* src, u16* dst){
  __builtin_amdgcn_global_load_lds(
      (const __attribute__((address_space(1))) unsigned int*)(u64)(src),
      (__attribute__((address_space(3))) unsigned int*)(u32)(u64)(dst),
      16, 0, 0);
}

// ---------------- x f32 -> bf16 one-shot convert (streaming) -------------------------
// Hoists the f2bf VALU + demand-f32 latency OUT of k_proj's inner loop (R20: 24%
// VALUBusy was conversions). xb aliases the U region (U not live until k_qk).
// Tensor size: B*S*D = 16*1024*512 = 8388608 elems (R21 launched 2x -> OOB fault).
__global__ __launch_bounds__(256) void k_xcvt(
    const float* __restrict__ xq, const float* __restrict__ xk, const float* __restrict__ xv,
    u16* __restrict__ xb)
{
  const int z = blockIdx.y;
  const float* x = (z == 0) ? xq : ((z == 1) ? xk : xv);
  const size_t i = ((size_t)blockIdx.x * 256 + threadIdx.x) * 8;   // < 8388608
  float4 f0 = *(const float4*)(x + i), f1 = *(const float4*)(x + i + 4);
  short8 v;
  v[0] = (short)f2bf(f0.x); v[1] = (short)f2bf(f0.y);
  v[2] = (short)f2bf(f0.z); v[3] = (short)f2bf(f0.w);
  v[4] = (short)f2bf(f1.x); v[5] = (short)f2bf(f1.y);
  v[6] = (short)f2bf(f1.z); v[7] = (short)f2bf(f1.w);
  *(short8*)(xb + (size_t)z * 8388608 + i) = v;
}

// ---------------- weight transpose+convert via LDS tiles (R19-proven) ----------------
__global__ __launch_bounds__(256) void k_wt6(
    const float* __restrict__ w0, const float* __restrict__ w1, const float* __restrict__ w2,
    const float* __restrict__ w3, const float* __restrict__ w4, const float* __restrict__ w5,
    u16* __restrict__ wts)
{
  __shared__ u16 T[64][66];
  const int z = blockIdx.z;
  const float* w;
  switch (z){ case 0: w = w0; break; case 1: w = w1; break; case 2: w = w2; break;
              case 3: w = w3; break; case 4: w = w4; break; default: w = w5; break; }
  const int j0 = blockIdx.x * 64, d0 = blockIdx.y * 64;
  const int c = threadIdx.x & 63, r = threadIdx.x >> 6;
  #pragma unroll
  for (int it = 0; it < 16; ++it){
    const int rr = it * 4 + r;
    T[c][rr] = f2bf(w[(size_t)(d0 + rr) * 512 + j0 + c]);
  }
  __syncthreads();
  u16* out = wts + (size_t)z * 262144;
  #pragma unroll
  for (int it = 0; it < 16; ++it){
    const int jr = it * 4 + r;
    out[(size_t)(j0 + jr) * 512 + d0 + c] = T[jr][c];
  }
}

// ---------------- 5-way projection GEMM v2: both operands via gl_lds16 ---------------
// A reads pre-converted bf16 xb (k_fc-identical staging). z: 0=Q(xq),1=K(xk),
// 2=V(xv,transposed out),3=Q1(xq),4=K1(xk).
__global__ __launch_bounds__(256) void k_proj(
    const u16* __restrict__ xb, const u16* __restrict__ wts,
    const float* __restrict__ bq, const float* __restrict__ bk, const float* __restrict__ bv,
    const float* __restrict__ bq1, const float* __restrict__ bk1,
    u16* __restrict__ Qh, u16* __restrict__ Kh, u16* __restrict__ Vt,
    u16* __restrict__ Q1h, u16* __restrict__ K1h)
{
  __shared__ __align__(16) u16 Asf[128 * 64];
  __shared__ __align__(16) u16 Bsf[128 * 64];
  const int z = blockIdx.z;
  const int xsel = (z == 3) ? 0 : ((z == 4) ? 1 : z);
  const u16* x = xb + (size_t)xsel * 8388608;
  const float* bias; u16* out; int vtm = 0;
  switch (z){
    case 0: bias = bq;  out = Qh;  break;
    case 1: bias = bk;  out = Kh;  break;
    case 2: bias = bv;  out = Vt;  vtm = 1; break;
    case 3: bias = bq1; out = Q1h; break;
    default: bias = bk1; out = K1h; break;
  }
  const u16* wt = wts + (size_t)z * 262144;
  const int tid = threadIdx.x, lane = tid & 63, wid = tid >> 6;
  const int wm = wid >> 1, wn = wid & 1;
  const int m0 = blockIdx.x * 128, n0 = blockIdx.y * 128;
  const int arow = lane & 15, kg = lane >> 4;
  const int br = tid >> 3, bc = tid & 7;
  u16* const adst = Asf + wid * 512;
  u16* const bdst = Bsf + wid * 512;

  floatx4 acc[4][4];
  #pragma unroll
  for (int i = 0; i < 4; ++i)
    #pragma unroll
    for (int j = 0; j < 4; ++j) acc[i][j] = Z4;

  for (int k0 = 0; k0 < 512; k0 += 64){
    #pragma unroll
    for (int q = 0; q < 4; ++q){
      gl_lds16(x  + (size_t)(m0 + q * 32 + br) * 512 + k0 + ((bc ^ (br & 7)) * 8),
               adst + q * 2048);
      gl_lds16(wt + (size_t)(n0 + q * 32 + br) * 512 + k0 + ((bc ^ (br & 7)) * 8),
               bdst + q * 2048);
    }
    __syncthreads();
    #pragma unroll
    for (int kk = 0; kk < 2; ++kk){
      short8 af[4], bf[4];
      #pragma unroll
      for (int mm = 0; mm < 4; ++mm){
        int rr = wm * 64 + mm * 16 + arow;
        af[mm] = *(const short8*)&Asf[rr * 64 + ((kk * 32 + kg * 8) ^ ((rr & 7) * 8))];
      }
      #pragma unroll
      for (int nn = 0; nn < 4; ++nn){
        int rr = wn * 64 + nn * 16 + arow;
        bf[nn] = *(const short8*)&Bsf[rr * 64 + ((kk * 32 + kg * 8) ^ ((rr & 7) * 8))];
      }
      #pragma unroll
      for (int mm = 0; mm < 4; ++mm)
        #pragma unroll
        for (int nn = 0; nn < 4; ++nn)
          acc[mm][nn] = MFMA16(af[mm], bf[nn], acc[mm][nn]);
    }
    __syncthreads();
  }
  #pragma unroll
  for (int mm = 0; mm < 4; ++mm)
    #pragma unroll
    for (int nn = 0; nn < 4; ++nn){
      int j = n0 + wn * 64 + nn * 16 + arow;
      int h = j >> 6, dh = j & 63;
      float bval = bias[j];
      #pragma unroll
      for (int i = 0; i < 4; ++i){
        int sg = m0 + wm * 64 + mm * 16 + kg * 4 + i;
        int bb = sg >> 10, s = sg & 1023;
        float val = acc[mm][nn][i] + bval;
        size_t o = vtm ? (((size_t)((bb << 3) + h) * 64 + dh) * 1024 + s)
                       : (((size_t)((bb << 3) + h) * 1024 + s) * 64 + dh);
        out[o] = f2bf(val);
      }
    }
}

// ================= SPLIT PATH =================
// ---------------- kernel A (R17-proven): k-outer / q-inner dual-QK -> U, rsum --------
__global__ void __launch_bounds__(1024)
k_qk(const u16* __restrict__ Qh, const u16* __restrict__ Kh,
     const u16* __restrict__ Q1h, const u16* __restrict__ K1h,
     const int* __restrict__ mask, u16* __restrict__ U, float* __restrict__ rsum)
{
  __shared__ __align__(16) u16 stg[2 * 8192];

  const int tid = threadIdx.x, lane = tid & 63, wid = tid >> 6;
  const int arow = lane & 15, kg = lane >> 4;
  const int b = blockIdx.x, h = blockIdx.y, qs = blockIdx.z;
  const size_t hb = (size_t)(b * 8 + h);

  const int qrow = qs * 256 + wid * 16 + arow;
  const u16* qp  = Qh  + (hb * 1024 + qrow) * 64 + kg * 8;
  const u16* q1p = Q1h + (hb * 1024 + qrow) * 64 + kg * 8;
  short8 aq0 = *(const short8*)qp,  aq1 = *(const short8*)(qp + 32);
  short8 ap0 = *(const short8*)q1p, ap1 = *(const short8*)(q1p + 32);

  u64 mb = 0;
  #pragma unroll
  for (int t = 0; t < 16; ++t)
    #pragma unroll
    for (int cs = 0; cs < 4; ++cs)
      mb |= (mask[b * 1024 + t * 64 + cs * 16 + arow] != 0 ? 1ull : 0ull) << (t * 4 + cs);

  const int ls_half = tid >> 9;
  const int ls_r = (tid & 511) >> 3;
  const int ls_c = (tid & 7) ^ (ls_r & 7);
  u16* const sbase = stg + wid * 512;
  const u16* lsrc = (ls_half ? Kh : K1h) + hb * 65536 + (size_t)ls_r * 64 + ls_c * 8;

  u16* const ubase = U + hb * 1048576;
  const int urow0 = qs * 256 + wid * 16 + kg * 4;

  gl_lds16(lsrc, sbase);
  __syncthreads();

  float sacc[4] = {0.f, 0.f, 0.f, 0.f};
  for (int t = 0; t < 16; ++t){
    if (t < 15)
      gl_lds16(lsrc + (size_t)(t + 1) * 4096, sbase + (((t + 1) & 1) << 13));
    const u16* kb = stg + ((t & 1) << 13);
    #pragma unroll
    for (int cs = 0; cs < 4; ++cs){
      const int krow = cs * 16 + arow;
      const int swl = (krow & 7) * 8;
      short8 b1a = *(const short8*)&kb[krow * 64 + ((     kg * 8) ^ swl)];
      short8 b1b = *(const short8*)&kb[krow * 64 + ((32 + kg * 8) ^ swl)];
      short8 bea = *(const short8*)&kb[4096 + krow * 64 + ((     kg * 8) ^ swl)];
      short8 beb = *(const short8*)&kb[4096 + krow * 64 + ((32 + kg * 8) ^ swl)];
      floatx4 cg4 = Z4, ce4 = Z4;
      cg4 = MFMA16(ap0, b1a, cg4); cg4 = MFMA16(ap1, b1b, cg4);
      ce4 = MFMA16(aq0, bea, ce4); ce4 = MFMA16(aq1, beb, ce4);
      const float msk = ((mb >> (t * 4 + cs)) & 1ull) ? 1.0f : 0.0f;
      #pragma unroll
      for (int i = 0; i < 4; ++i){
        float p = fexp2(ce4[i] * KEXP) * msk;
        float g = frcp(1.0f + fexp2(-cg4[i] * KEXP));
        sacc[i] += p;
        ubase[(size_t)(urow0 + i) * 1024 + t * 64 + cs * 16 + arow] = f2bf(p * g);
      }
    }
    __syncthreads();
  }

  #pragma unroll
  for (int i = 0; i < 4; ++i){
    #pragma unroll
    for (int off = 1; off <= 8; off <<= 1)
      sacc[i] += __shfl_xor(sacc[i], off, 64);
  }
  if (arow == 0){
    #pragma unroll
    for (int i = 0; i < 4; ++i)
      rsum[hb * 1024 + urow0 + i] = sacc[i];
  }
}

// ---------------- kernel B v4 (R20-proven): 64-row blocks, r_att + PV ----------------
__global__ void __launch_bounds__(1024)
__attribute__((amdgpu_waves_per_eu(4, 4)))
k_pvr(const u16* __restrict__ U, const float* __restrict__ rsum,
      const u16* __restrict__ Vt, u16* __restrict__ xa, float* __restrict__ ratt)
{
  extern __shared__ __align__(16) u16 stg2[];   // 2 bufs x 16384 u16: U[0,8192) V[8192,16384)

  const int tid = threadIdx.x, lane = tid & 63, wid = tid >> 6;
  const int arow = lane & 15, kg = lane >> 4;
  const int b = blockIdx.x, qt = blockIdx.y;
  const int rs = wid & 3, cs2 = wid >> 2;
  const int cres = cs2 * 16 + arow;
  const int wrow = wid * 4;
  const int a_r = rs * 16 + arow;

  const int ur = tid >> 4, uc = (tid & 15) ^ (ur & 7);

  float racc[4][16];
  #pragma unroll
  for (int r = 0; r < 4; ++r)
    #pragma unroll
    for (int j = 0; j < 16; ++j) racc[r][j] = 0.f;

  for (int h = 0; h < 8; ++h){
    const size_t hb = (size_t)(b * 8 + h);
    const u16* ub = U  + hb * 1048576 + (size_t)(qt * 64) * 1024;
    const u16* vb = Vt + hb * 65536;

    float rlh[4], rlx[4];
    #pragma unroll
    for (int r = 0; r < 4; ++r)
      rlh[r] = frcp(rsum[hb * 1024 + qt * 64 + wrow + r]) * 0.125f;
    #pragma unroll
    for (int i = 0; i < 4; ++i)
      rlx[i] = frcp(rsum[hb * 1024 + qt * 64 + rs * 16 + kg * 4 + i]);

    gl_lds16(ub + (size_t)ur * 1024 + uc * 8, stg2 + tid * 8);
    gl_lds16(vb + (size_t)ur * 1024 + uc * 8, stg2 + 8192 + tid * 8);
    __syncthreads();

    floatx4 cpv = Z4;
    for (int t = 0; t < 8; ++t){
      if (t < 7){
        const int nb = ((t + 1) & 1) * 16384;
        gl_lds16(ub + (size_t)ur * 1024 + (t + 1) * 128 + uc * 8, stg2 + nb + tid * 8);
        gl_lds16(vb + (size_t)ur * 1024 + (t + 1) * 128 + uc * 8, stg2 + nb + 8192 + tid * 8);
      }
      const u16* Ut  = stg2 + (t & 1) * 16384;
      const u16* Vts = Ut + 8192;
      #pragma unroll
      for (int r = 0; r < 4; ++r){
        const int row = wrow + r;
        u32 w = *(const u32*)&Ut[row * 128 + ((lane * 2) ^ ((row & 7) * 8))];
        racc[r][2 * t]     += __uint_as_float(w << 16) * rlh[r];
        racc[r][2 * t + 1] += __uint_as_float(w & 0xFFFF0000u) * rlh[r];
      }
      #pragma unroll
      for (int ks = 0; ks < 4; ++ks){
        short8 a  = *(const short8*)&Ut[a_r * 128 + ((ks * 32 + kg * 8) ^ ((a_r & 7) * 8))];
        short8 bv = *(const short8*)&Vts[cres * 128 + ((ks * 32 + kg * 8) ^ ((cres & 7) * 8))];
        cpv = MFMA16(a, bv, cpv);
      }
      __syncthreads();
    }
    #pragma unroll
    for (int i = 0; i < 4; ++i){
      const int g = qt * 64 + rs * 16 + kg * 4 + i;
      xa[((size_t)(b * 1024 + g)) * 512 + h * 64 + cres] = f2bf(cpv[i] * rlx[i]);
    }
  }

  #pragma unroll
  for (int r = 0; r < 4; ++r){
    const size_t rb = ((size_t)(b * 1024 + qt * 64 + wrow + r)) * 1024;
    #pragma unroll
    for (int j = 0; j < 8; ++j){
      float2 v = {racc[r][2 * j], racc[r][2 * j + 1]};
      *(float2*)&ratt[rb + j * 128 + lane * 2] = v;
    }
  }
}

// ---------------- final FC, 128x128 tile (R14-proven) ----------------
__global__ __launch_bounds__(256) void k_fc(
    const u16* __restrict__ xa, const u16* __restrict__ wt,
    const float* __restrict__ bias, float* __restrict__ out)
{
  __shared__ __align__(16) u16 Asf[128 * 64];
  __shared__ __align__(16) u16 Bsf[128 * 64];
  const int tid = threadIdx.x, lane = tid & 63, wid = tid >> 6;
  const int wm = wid >> 1, wn = wid & 1;
  const int m0 = blockIdx.x * 128, n0 = blockIdx.y * 128;
  const int arow = lane & 15, kg = lane >> 4;
  const int br = tid >> 3, bc = tid & 7;
  u16* const adst = Asf + wid * 512;
  u16* const bdst = Bsf + wid * 512;

  floatx4 acc[4][4];
  #pragma unroll
  for (int i = 0; i < 4; ++i)
    #pragma unroll
    for (int j = 0; j < 4; ++j) acc[i][j] = Z4;

  for (int k0 = 0; k0 < 512; k0 += 64){
    #pragma unroll
    for (int q = 0; q < 4; ++q){
      gl_lds16(xa + (size_t)(m0 + q * 32 + br) * 512 + k0 + ((bc ^ (br & 7)) * 8),
               adst + q * 2048);
      gl_lds16(wt + (size_t)(n0 + q * 32 + br) * 512 + k0 + ((bc ^ (br & 7)) * 8),
               bdst + q * 2048);
    }
    __syncthreads();
    #pragma unroll
    for (int kk = 0; kk < 2; ++kk){
      short8 af[4], bf[4];
      #pragma unroll
      for (int mm = 0; mm < 4; ++mm){
        int rr = wm * 64 + mm * 16 + arow;
        af[mm] = *(const short8*)&Asf[rr * 64 + ((kk * 32 + kg * 8) ^ ((rr & 7) * 8))];
      }
      #pragma unroll
      for (int nn = 0; nn < 4; ++nn){
        int rr = wn * 64 + nn * 16 + arow;
        bf[nn] = *(const short8*)&Bsf[rr * 64 + ((kk * 32 + kg * 8) ^ ((rr & 7) * 8))];
      }
      #pragma unroll
      for (int mm = 0; mm < 4; ++mm)
        #pragma unroll
        for (int nn = 0; nn < 4; ++nn)
          acc[mm][nn] = MFMA16(af[mm], bf[nn], acc[mm][nn]);
    }
    __syncthreads();
  }
  #pragma unroll
  for (int mm = 0; mm < 4; ++mm)
    #pragma unroll
    for (int nn = 0; nn < 4; ++nn){
      int j = n0 + wn * 64 + nn * 16 + arow;
      float bval = bias[j];
      #pragma unroll
      for (int i = 0; i < 4; ++i){
        int sg = m0 + wm * 64 + mm * 16 + kg * 4 + i;
        out[(size_t)sg * 512 + j] = acc[mm][nn][i] + bval;
      }
    }
}

extern "C" void kernel_launch(void* const* d_in, const int* in_sizes, int n_in,
                              void* d_out, int out_size, void* d_ws, size_t ws_size,
                              hipStream_t stream)
{
  const float* query = (const float*)d_in[0];
  const float* key   = (const float*)d_in[1];
  const float* value = (const float*)d_in[2];
  const int*   mask  = (const int*)d_in[3];
  const float* wq  = (const float*)d_in[4];  const float* bq  = (const float*)d_in[5];
  const float* wk  = (const float*)d_in[6];  const float* bk  = (const float*)d_in[7];
  const float* wv  = (const float*)d_in[8];  const float* bv  = (const float*)d_in[9];
  const float* wq1 = (const float*)d_in[10]; const float* bq1 = (const float*)d_in[11];
  const float* wk1 = (const float*)d_in[12]; const float* bk1 = (const float*)d_in[13];
  const float* wfc = (const float*)d_in[14]; const float* bfc = (const float*)d_in[15];

  u16* ws  = (u16*)d_ws;
  u16* Qh  = ws;
  u16* Kh  = Qh  + 8388608;
  u16* Vt  = Kh  + 8388608;
  u16* Q1h = Vt  + 8388608;
  u16* K1h = Q1h + 8388608;
  u16* xa  = K1h + 8388608;
  u16* wts = xa  + 8388608;           // 6 * 262144 u16
  u16* U   = wts + 6 * 262144;        // 134217728 u16 = 268 MB
  float* rsum = (float*)(U + 134217728);  // 131072 f32
  u16* xb  = U;                       // bf16 x (3 x 8388608 u16 = 50 MB), aliased over
                                      // U: written by k_xcvt, read by k_proj, dead
                                      // before k_qk writes U.

  float* outx = (float*)d_out;
  float* ratt = outx + 8388608;

  k_wt6<<<dim3(8, 8, 6), dim3(256), 0, stream>>>(wq, wk, wv, wq1, wk1, wfc, wts);

  k_xcvt<<<dim3(4096, 3), dim3(256), 0, stream>>>(query, key, value, xb);

  k_proj<<<dim3(128, 4, 5), dim3(256), 0, stream>>>(
      xb, wts, bq, bk, bv, bq1, bk1, Qh, Kh, Vt, Q1h, K1h);

  (void)hipFuncSetAttribute((const void*)k_pvr,
                            hipFuncAttributeMaxDynamicSharedMemorySize, 65536);
  k_qk<<<dim3(16, 8, 4), dim3(1024), 0, stream>>>(
      Qh, Kh, Q1h, K1h, mask, U, rsum);
  k_pvr<<<dim3(16, 16), dim3(1024), 65536, stream>>>(
      U, rsum, Vt, xa, ratt);

  k_fc<<<dim3(128, 4), dim3(256), 0, stream>>>(
      xa, wts + 5 * 262144, bfc, outx);
}